// Round 14
// baseline (761.403 us; speedup 1.0000x reference)
//
#include <hip/hip_runtime.h>
#include <hip/hip_bf16.h>
#include <hip/hip_cooperative_groups.h>
#include <math.h>

namespace cg = cooperative_groups;

// B=1, C=32, H=D=W=32, N=32768, modes 16^3 (z 0..15 of 17), KS=3, MEM=5
#define NSP 32768
#define NZ 17

typedef float f4_t __attribute__((ext_vector_type(4)));

__device__ __forceinline__ float geluf(float x){
    return 0.5f * x * (1.0f + erff(x * 0.70710678118654752f));
}
__device__ __forceinline__ float sigmoidf_(float x){
    return 1.0f / (1.0f + __expf(-x));
}
__device__ __forceinline__ float wavesum(float v){
    #pragma unroll
    for (int off = 32; off > 0; off >>= 1) v += __shfl_down(v, off, 64);
    return v;
}

struct MegaParams {
    const float *x, *tin, *pm;
    const float *wsr, *wsi;
    const float *n1g, *n1b;
    const float *mw1, *mb1, *mw2, *mb2;
    const float *tgw, *tgb, *tbw, *tbb;
    const float *qw, *qb, *kw, *kb, *vw, *vb;
    const float *mk, *mv, *gw, *gb;
    const float *wih, *whh, *bih, *bhh;
    float *Ar, *Ai, *Br, *Bi, *spec, *h1, *h2, *h3;
    float *psum, *psq, *psum2, *psq2;
    float *outp;
};

union SMem {
    struct { float tile[32*33]; float ar[544], ai[544]; } fwd;
    struct { float ir[544], ii[544]; } ffth;
    struct { float ir[544], ii[544], cr[544], ci[544]; } inv;
    struct { float W1[512], W2[512], B1[16], B2[32], GG[32], BB[32]; } mlp;
    struct { float QW[1024], KW[1024], VW[1024], GA[32], BE[32], QB[32]; } qkv;
    struct { float KL[3][1024], VL[3][1024]; } attn;
    struct { float GW[2048]; float WS[4][32]; } gate;
    struct { float PS[256]; float m_in[32], gi[96], gh[96]; } gru;
};

// ---------------- cooperative mega-kernel: grid 512 x 256 ----------------
__global__ void __launch_bounds__(256, 4) k_mega(MegaParams P){
    cg::grid_group grid = cg::this_grid();
    __shared__ SMem sm;
    __shared__ float ls[256], lq[256];
    __shared__ float ct[32], st[32];
    int b0 = blockIdx.x, t = threadIdx.x;
    if (t < 32){ float ang = 6.283185307179586477f * (float)t / 32.0f; ct[t] = cosf(ang); st[t] = sinf(ang); }
    __syncthreads();

    // ---- Phase 1: rfft_w + fft_d. virtual block = (c*32+h). x -> Br,Bi ----
    for (int b = b0; b < 1024; b += 512){
        const float* src = P.x + b * 1024;
        for (int j = t; j < 1024; j += 256) sm.fwd.tile[(j & 31) * 33 + (j >> 5)] = src[j];
        __syncthreads();
        for (int idx = t; idx < 544; idx += 256){
            int d = idx / 17, z = idx - d * 17;
            float sr = 0.f, si = 0.f;
            #pragma unroll
            for (int w = 0; w < 32; ++w){
                int a = (z * w) & 31;
                float v = sm.fwd.tile[w * 33 + d];
                sr += v * ct[a];
                si -= v * st[a];
            }
            sm.fwd.ar[idx] = sr; sm.fwd.ai[idx] = si;
        }
        __syncthreads();
        for (int idx = t; idx < 544; idx += 256){
            int kd = idx / 17, z = idx - kd * 17;
            float sr = 0.f, si = 0.f;
            #pragma unroll
            for (int d = 0; d < 32; ++d){
                int a = (kd * d) & 31;
                float c = ct[a], s = st[a];
                float vr = sm.fwd.ar[d * 17 + z], vi = sm.fwd.ai[d * 17 + z];
                sr += vr * c + vi * s;      // e^{-i}
                si += vi * c - vr * s;
            }
            P.Br[b * 544 + idx] = sr; P.Bi[b * 544 + idx] = si;
        }
        __syncthreads();
    }
    grid.sync();

    // ---- Phase 2: fft_h. virtual block = (c*32+d). Br,Bi -> Ar,Ai ----
    for (int b = b0; b < 1024; b += 512){
        int c = b >> 5, d = b & 31;
        for (int j = t; j < 544; j += 256){
            int h = j / 17, z = j - h * 17;
            int g = ((c * 32 + h) * 32 + d) * NZ + z;
            sm.ffth.ir[j] = P.Br[g]; sm.ffth.ii[j] = P.Bi[g];
        }
        __syncthreads();
        for (int idx = t; idx < 544; idx += 256){
            int kh = idx / 17, z = idx - kh * 17;
            float sr = 0.f, si = 0.f;
            #pragma unroll
            for (int h = 0; h < 32; ++h){
                int a = (kh * h) & 31;
                float c2 = ct[a], s2 = st[a];
                float vr = sm.ffth.ir[h * 17 + z], vi = sm.ffth.ii[h * 17 + z];
                sr += vr * c2 + vi * s2;
                si += vi * c2 - vr * s2;
            }
            int g = ((c * 32 + kh) * 32 + d) * NZ + z;
            P.Ar[g] = sr; P.Ai[g] = si;
        }
        __syncthreads();
    }
    grid.sync();

    // ---- Phase 3: modemul (512 blocks, 1:1). Ar,Ai x W -> Br,Bi ----
    {
        int b = b0;
        int q = b & 3;
        int o = (b >> 2) & 31;
        int corner = b >> 7;
        int m = q * 1024 + t * 4;
        int xm = m >> 8, ym = (m >> 4) & 15, zm = m & 15;
        int xg = xm + ((corner & 1) << 4);
        int y  = ym + ((corner >> 1) << 4);
        if (t < 128){
            int xl = t >> 5;
            int arr = (t >> 4) & 1;
            int yl = t & 15;
            int xgz = q * 4 + xl + ((corner & 1) << 4);
            int yz = yl + ((corner >> 1) << 4);
            int g = ((o * 32 + xgz) * 32 + yz) * NZ + 16;
            if (arr == 0) P.Br[g] = 0.f; else P.Bi[g] = 0.f;
        }
        size_t xoff = (size_t)(xg * 32 + y) * NZ + zm;
        const float* wr = P.wsr + (size_t)((corner * 32) * 32 + o) * 4096 + m;
        const float* wi = P.wsi + (size_t)((corner * 32) * 32 + o) * 4096 + m;
        float ar0=0.f, ar1=0.f, ar2=0.f, ar3=0.f;
        float ai0=0.f, ai1=0.f, ai2=0.f, ai3=0.f;
        #pragma unroll 4
        for (int i = 0; i < 32; ++i){
            f4_t w4r = __builtin_nontemporal_load((const f4_t*)(wr + (size_t)i * 131072));
            f4_t w4i = __builtin_nontemporal_load((const f4_t*)(wi + (size_t)i * 131072));
            const float* pxr = P.Ar + (size_t)i * 17408 + xoff;
            const float* pxi = P.Ai + (size_t)i * 17408 + xoff;
            float xr0 = pxr[0], xr1 = pxr[1], xr2 = pxr[2], xr3 = pxr[3];
            float xi0 = pxi[0], xi1 = pxi[1], xi2 = pxi[2], xi3 = pxi[3];
            ar0 += w4r.x * xr0 - w4i.x * xi0;  ai0 += w4r.x * xi0 + w4i.x * xr0;
            ar1 += w4r.y * xr1 - w4i.y * xi1;  ai1 += w4r.y * xi1 + w4i.y * xr1;
            ar2 += w4r.z * xr2 - w4i.z * xi2;  ai2 += w4r.z * xi2 + w4i.z * xr2;
            ar3 += w4r.w * xr3 - w4i.w * xi3;  ai3 += w4r.w * xi3 + w4i.w * xr3;
        }
        int g = ((o * 32 + xg) * 32 + y) * NZ + zm;
        P.Br[g + 0] = ar0; P.Br[g + 1] = ar1; P.Br[g + 2] = ar2; P.Br[g + 3] = ar3;
        P.Bi[g + 0] = ai0; P.Bi[g + 1] = ai1; P.Bi[g + 2] = ai2; P.Bi[g + 3] = ai3;
    }
    grid.sync();

    // ---- Phase 4: ifft_h. virtual block = (c*32+y). Br,Bi -> Ar,Ai ----
    for (int b = b0; b < 1024; b += 512){
        int c = b >> 5, y = b & 31;
        for (int j = t; j < 544; j += 256){
            int xk = j / 17, z = j - xk * 17;
            int g = ((c * 32 + xk) * 32 + y) * NZ + z;
            sm.ffth.ir[j] = P.Br[g]; sm.ffth.ii[j] = P.Bi[g];
        }
        __syncthreads();
        for (int idx = t; idx < 544; idx += 256){
            int h = idx / 17, z = idx - h * 17;
            float sr = 0.f, si = 0.f;
            #pragma unroll
            for (int k = 0; k < 32; ++k){
                int a = (k * h) & 31;
                float c2 = ct[a], s2 = st[a];
                float vr = sm.ffth.ir[k * 17 + z], vi = sm.ffth.ii[k * 17 + z];
                sr += vr * c2 - vi * s2;    // e^{+i}
                si += vr * s2 + vi * c2;
            }
            int g = ((c * 32 + h) * 32 + y) * NZ + z;
            P.Ar[g] = sr; P.Ai[g] = si;
        }
        __syncthreads();
    }
    grid.sync();

    // ---- Phase 5: ifft_d + irfft_w + GN1 partials. virtual block = (c*32+h) ----
    for (int b = b0; b < 1024; b += 512){
        const float* pr = P.Ar + b * 544;
        const float* pi = P.Ai + b * 544;
        for (int j = t; j < 544; j += 256){ sm.inv.ir[j] = pr[j]; sm.inv.ii[j] = pi[j]; }
        __syncthreads();
        for (int idx = t; idx < 544; idx += 256){
            int d = idx / 17, z = idx - d * 17;
            float sr = 0.f, si = 0.f;
            #pragma unroll
            for (int k = 0; k < 32; ++k){
                int a = (k * d) & 31;
                float c2 = ct[a], s2 = st[a];
                float vr = sm.inv.ir[k * 17 + z], vi = sm.inv.ii[k * 17 + z];
                sr += vr * c2 - vi * s2;
                si += vr * s2 + vi * c2;
            }
            sm.inv.cr[idx] = sr; sm.inv.ci[idx] = si;
        }
        __syncthreads();
        const float inv = 1.0f / 32768.0f;
        float s_loc = 0.f, q_loc = 0.f;
        for (int idx = t; idx < 1024; idx += 256){
            int d = idx >> 5, w = idx & 31;
            float s = sm.inv.cr[d * 17 + 0] + ((w & 1) ? -sm.inv.cr[d * 17 + 16] : sm.inv.cr[d * 17 + 16]);
            #pragma unroll
            for (int z = 1; z < 16; ++z){
                int a = (z * w) & 31;
                s += 2.0f * (sm.inv.cr[d * 17 + z] * ct[a] - sm.inv.ci[d * 17 + z] * st[a]);
            }
            s *= inv;
            P.spec[b * 1024 + idx] = s;
            s_loc += s; q_loc += s * s;
        }
        ls[t] = s_loc; lq[t] = q_loc; __syncthreads();
        for (int off = 128; off > 0; off >>= 1){
            if (t < off){ ls[t] += ls[t + off]; lq[t] += lq[t + off]; }
            __syncthreads();
        }
        if (t == 0){ P.psum[b] = ls[0]; P.psq[b] = lq[0]; }
        __syncthreads();
    }
    grid.sync();

    // ---- Phase 6: GN1 finalize + MLP + GN2 partials (blocks < 128) ----
    if (b0 < 128){
        int b = b0;
        for (int j = t; j < 512; j += 256){ sm.mlp.W1[j] = P.mw1[j]; sm.mlp.W2[j] = P.mw2[j]; }
        if (t < 16) sm.mlp.B1[t] = P.mb1[t];
        if (t < 32){ sm.mlp.B2[t] = P.mb2[t]; sm.mlp.GG[t] = P.n1g[t]; sm.mlp.BB[t] = P.n1b[t]; }
        float s0 = 0.f, q0 = 0.f;
        for (int j = t; j < 1024; j += 256){ s0 += P.psum[j]; q0 += P.psq[j]; }
        ls[t] = s0; lq[t] = q0; __syncthreads();
        for (int off = 128; off > 0; off >>= 1){
            if (t < off){ ls[t] += ls[t + off]; lq[t] += lq[t + off]; }
            __syncthreads();
        }
        float mu = ls[0] * (1.0f / 1048576.0f);
        float var = lq[0] * (1.0f / 1048576.0f) - mu * mu;
        float rs = rsqrtf(var + 1e-5f);
        __syncthreads();
        int n = b * 256 + t;
        float hv[32];
        #pragma unroll
        for (int c = 0; c < 32; ++c){
            float v = (P.spec[c * NSP + n] - mu) * rs * sm.mlp.GG[c] + sm.mlp.BB[c] + P.x[c * NSP + n];
            hv[c] = geluf(v);
        }
        float u[16];
        #pragma unroll
        for (int o = 0; o < 16; ++o){
            float a = sm.mlp.B1[o];
            #pragma unroll
            for (int c = 0; c < 32; ++c) a += sm.mlp.W1[o * 32 + c] * hv[c];
            u[o] = geluf(a);
        }
        float s_loc = 0.f, q_loc = 0.f;
        #pragma unroll
        for (int o = 0; o < 32; ++o){
            float a = sm.mlp.B2[o];
            #pragma unroll
            for (int c = 0; c < 16; ++c) a += sm.mlp.W2[o * 16 + c] * u[c];
            P.h2[o * NSP + n] = a;
            s_loc += a; q_loc += a * a;
        }
        ls[t] = s_loc; lq[t] = q_loc; __syncthreads();
        for (int off = 128; off > 0; off >>= 1){
            if (t < off){ ls[t] += ls[t + off]; lq[t] += lq[t + off]; }
            __syncthreads();
        }
        if (t == 0){ P.psum2[b] = ls[0]; P.psq2[b] = lq[0]; }
    }
    grid.sync();

    // ---- Phase 7: GN2 finalize + TIN + QKV (blocks < 128). h2 -> h3, Q(Br), KH(spec), VH(h1) ----
    if (b0 < 128){
        int b = b0;
        for (int j = t; j < 1024; j += 256){ sm.qkv.QW[j] = P.qw[j]; sm.qkv.KW[j] = P.kw[j]; sm.qkv.VW[j] = P.vw[j]; }
        if (t < 32) sm.qkv.QB[t] = P.qb[t];
        ls[t] = (t < 128) ? P.psum2[t] : 0.f;
        lq[t] = (t < 128) ? P.psq2[t] : 0.f;
        __syncthreads();
        for (int off = 128; off > 0; off >>= 1){
            if (t < off){ ls[t] += ls[t + off]; lq[t] += lq[t + off]; }
            __syncthreads();
        }
        float mu = ls[0] * (1.0f / 1048576.0f);
        float var = lq[0] * (1.0f / 1048576.0f) - mu * mu;
        float rs = rsqrtf(var + 1e-5f);
        __syncthreads();
        if (t < 64){
            int o = t & 31;
            const float* w = (t < 32) ? P.tgw : P.tbw;
            const float* bi = (t < 32) ? P.tgb : P.tbb;
            float a = bi[o];
            #pragma unroll
            for (int c = 0; c < 32; ++c) a += w[o * 32 + c] * P.tin[c];
            if (t < 32) sm.qkv.GA[o] = a; else sm.qkv.BE[o] = a;
        }
        __syncthreads();
        int n = b * 256 + t;
        float hv[32];
        #pragma unroll
        for (int c = 0; c < 32; ++c){
            float v = sm.qkv.GA[c] * ((P.h2[c * NSP + n] - mu) * rs) + sm.qkv.BE[c];
            hv[c] = v;
            P.h3[c * NSP + n] = v;
        }
        #pragma unroll
        for (int o = 0; o < 32; ++o){
            float aq = sm.qkv.QB[o], ak = 0.f, av = 0.f;
            #pragma unroll
            for (int c = 0; c < 32; ++c){
                float v = hv[c];
                aq += sm.qkv.QW[o * 32 + c] * v;
                ak += sm.qkv.KW[o * 32 + c] * v;
                av += sm.qkv.VW[o * 32 + c] * v;
            }
            P.Br[o * NSP + n] = aq;      // Q
            P.spec[o * NSP + n] = ak;    // KH
            P.h1[o * NSP + n] = av;      // VH
        }
    }
    grid.sync();

    // ---- Phase 8: attention. virtual block -> (c,h) via XCD swizzle. -> out0 (Ar) ----
    for (int b = b0; b < 1024; b += 512){
        int swz = (b & 7) * 128 + (b >> 3);
        int c = swz >> 5, h_ = swz & 31;
        const float* Q  = P.Br;
        const float* KH = P.spec;
        const float* VH = P.h1;
        #pragma unroll
        for (int p = 0; p < 3; ++p){
            int hh = h_ - 1 + p;
            if ((unsigned)hh < 32u){
                const float* sk = KH + (c * 32 + hh) * 1024;
                const float* sv = VH + (c * 32 + hh) * 1024;
                for (int j = t; j < 1024; j += 256){ sm.attn.KL[p][j] = sk[j]; sm.attn.VL[p][j] = sv[j]; }
            }
        }
        float kbc = P.kb[c], vbc = P.vb[c];
        float mkv[5], mvv[5];
        #pragma unroll
        for (int j = 0; j < 5; ++j){ mkv[j] = P.mk[c * 5 + j]; mvv[j] = P.mv[c * 5 + j]; }
        float qv[4];
        #pragma unroll
        for (int i = 0; i < 4; ++i) qv[i] = Q[c * NSP + h_ * 1024 + i * 256 + t];
        __syncthreads();
        const float scale = 0.17677669529663688f; // 1/sqrt(32)
        #pragma unroll
        for (int i = 0; i < 4; ++i){
            int nl = i * 256 + t;
            int d_ = nl >> 5, w_ = nl & 31;
            float q = qv[i];
            float s = 0.f, acc = 0.f;
            #pragma unroll
            for (int j = 0; j < 5; ++j){
                float e = __expf(q * mkv[j] * scale);
                s += e; acc += e * mvv[j];
            }
            int oob = 0;
            #pragma unroll
            for (int p = 0; p < 3; ++p){
                int hh = h_ - 1 + p;
                if ((unsigned)hh >= 32u){ oob += 9; continue; }
                #pragma unroll
                for (int dj = -1; dj <= 1; ++dj){
                    int dd = d_ + dj;
                    if ((unsigned)dd >= 32u){ oob += 3; continue; }
                    int rb = dd * 32;
                    #pragma unroll
                    for (int dl = -1; dl <= 1; ++dl){
                        int ww = w_ + dl;
                        if ((unsigned)ww < 32u){
                            float k = kbc + sm.attn.KL[p][rb + ww];
                            float v = vbc + sm.attn.VL[p][rb + ww];
                            float e = __expf(q * k * scale);
                            s += e; acc += e * v;
                        } else oob++;
                    }
                }
            }
            float eb = __expf(q * kbc * scale);
            s += (float)oob * eb; acc += (float)oob * eb * vbc;
            P.Ar[c * NSP + h_ * 1024 + nl] = acc / s;   // out0
        }
        __syncthreads();
    }
    grid.sync();

    // ---- Phase 9: gate + output + channel partials (blocks < 128). -> outp, mpart (h2) ----
    if (b0 < 128){
        int b = b0;
        for (int j = t; j < 2048; j += 256) sm.gate.GW[j] = P.gw[j];
        __syncthreads();
        int n = b * 256 + t;
        int lane = t & 63, wv = t >> 6;
        float hv[32], ov[32];
        #pragma unroll
        for (int c = 0; c < 32; ++c){ hv[c] = P.h3[c * NSP + n]; ov[c] = P.Ar[c * NSP + n]; }
        #pragma unroll
        for (int c = 0; c < 32; ++c){
            float g = P.gb[c];
            #pragma unroll
            for (int cc = 0; cc < 32; ++cc){
                g += sm.gate.GW[c * 64 + cc] * hv[cc] + sm.gate.GW[c * 64 + 32 + cc] * ov[cc];
            }
            g = sigmoidf_(g);
            float fin = g * ov[c] + (1.0f - g) * hv[c];
            P.outp[c * NSP + n] = fin + geluf(P.x[c * NSP + n]);
            float ssum = wavesum(fin);
            if (lane == 0) sm.gate.WS[wv][c] = ssum;
        }
        __syncthreads();
        if (t < 32){
            float s = sm.gate.WS[0][t] + sm.gate.WS[1][t] + sm.gate.WS[2][t] + sm.gate.WS[3][t];
            P.h2[t * 128 + b] = s;   // mpart
        }
    }
    grid.sync();

    // ---- Phase 10: channel mean + GRU (block 0) ----
    if (b0 == 0){
        {
            int c = t >> 3, seg = t & 7;
            float s = 0.f;
            #pragma unroll
            for (int j = 0; j < 16; ++j) s += P.h2[c * 128 + seg * 16 + j];
            sm.gru.PS[t] = s;
        }
        __syncthreads();
        if (t < 32){
            float a = 0.f;
            #pragma unroll
            for (int j = 0; j < 8; ++j) a += sm.gru.PS[t * 8 + j];
            sm.gru.m_in[t] = a * (1.0f / 32768.0f);
        }
        __syncthreads();
        if (t < 96){
            float a = P.bih[t], b2 = P.bhh[t];
            #pragma unroll
            for (int cc = 0; cc < 32; ++cc){
                a += P.wih[t * 32 + cc] * sm.gru.m_in[cc];
                b2 += P.whh[t * 32 + cc] * P.pm[cc];
            }
            sm.gru.gi[t] = a; sm.gru.gh[t] = b2;
        }
        __syncthreads();
        if (t < 32){
            float r = sigmoidf_(sm.gru.gi[t] + sm.gru.gh[t]);
            float z = sigmoidf_(sm.gru.gi[32 + t] + sm.gru.gh[32 + t]);
            float nn = tanhf(sm.gru.gi[64 + t] + r * sm.gru.gh[64 + t]);
            float nm = (1.0f - z) * nn + z * P.pm[t];
            P.outp[1048576 + t] = nm;
        }
    }
}

// ================= fallback multi-kernel chain (proven, round 12) =================

__global__ void k_fwd(const float* __restrict__ x, float* __restrict__ Br, float* __restrict__ Bi){
    __shared__ float tile[32*33];
    __shared__ float ar[544], ai[544];
    __shared__ float ct[32], st[32];
    int b = blockIdx.x, t = threadIdx.x;
    if (t < 32){ float ang = 6.283185307179586477f * (float)t / 32.0f; ct[t] = cosf(ang); st[t] = sinf(ang); }
    const float* src = x + b * 1024;
    for (int j = t; j < 1024; j += 256) tile[(j & 31) * 33 + (j >> 5)] = src[j];
    __syncthreads();
    for (int idx = t; idx < 544; idx += 256){
        int d = idx / 17, z = idx - d * 17;
        float sr = 0.f, si = 0.f;
        #pragma unroll
        for (int w = 0; w < 32; ++w){
            int a = (z * w) & 31;
            float v = tile[w * 33 + d];
            sr += v * ct[a];
            si -= v * st[a];
        }
        ar[idx] = sr; ai[idx] = si;
    }
    __syncthreads();
    for (int idx = t; idx < 544; idx += 256){
        int kd = idx / 17, z = idx - kd * 17;
        float sr = 0.f, si = 0.f;
        #pragma unroll
        for (int d = 0; d < 32; ++d){
            int a = (kd * d) & 31;
            float c = ct[a], s = st[a];
            float vr = ar[d * 17 + z], vi = ai[d * 17 + z];
            sr += vr * c + vi * s;
            si += vi * c - vr * s;
        }
        Br[b * 544 + idx] = sr; Bi[b * 544 + idx] = si;
    }
}

__global__ void k_fft_h(const float* __restrict__ Br, const float* __restrict__ Bi,
                        float* __restrict__ Ar, float* __restrict__ Ai){
    __shared__ float ir[544], ii[544];
    __shared__ float ct[32], st[32];
    int b = blockIdx.x, t = threadIdx.x;
    int c = b >> 5, d = b & 31;
    if (t < 32){ float ang = 6.283185307179586477f * (float)t / 32.0f; ct[t] = cosf(ang); st[t] = sinf(ang); }
    for (int j = t; j < 544; j += 256){
        int h = j / 17, z = j - h * 17;
        int g = ((c * 32 + h) * 32 + d) * NZ + z;
        ir[j] = Br[g]; ii[j] = Bi[g];
    }
    __syncthreads();
    for (int idx = t; idx < 544; idx += 256){
        int kh = idx / 17, z = idx - kh * 17;
        float sr = 0.f, si = 0.f;
        #pragma unroll
        for (int h = 0; h < 32; ++h){
            int a = (kh * h) & 31;
            float c2 = ct[a], s2 = st[a];
            float vr = ir[h * 17 + z], vi = ii[h * 17 + z];
            sr += vr * c2 + vi * s2;
            si += vi * c2 - vr * s2;
        }
        int g = ((c * 32 + kh) * 32 + d) * NZ + z;
        Ar[g] = sr; Ai[g] = si;
    }
}

__global__ void k_modemul(const float* __restrict__ Xr, const float* __restrict__ Xi,
                          const float* __restrict__ Wr, const float* __restrict__ Wi,
                          float* __restrict__ Or, float* __restrict__ Oi){
    int b = blockIdx.x;
    int q = b & 3;
    int o = (b >> 2) & 31;
    int corner = b >> 7;
    int t = threadIdx.x;
    int m = q * 1024 + t * 4;
    int xm = m >> 8, ym = (m >> 4) & 15, zm = m & 15;
    int xg = xm + ((corner & 1) << 4);
    int y  = ym + ((corner >> 1) << 4);
    if (t < 128){
        int xl = t >> 5;
        int arr = (t >> 4) & 1;
        int yl = t & 15;
        int xgz = q * 4 + xl + ((corner & 1) << 4);
        int yz = yl + ((corner >> 1) << 4);
        int g = ((o * 32 + xgz) * 32 + yz) * NZ + 16;
        if (arr == 0) Or[g] = 0.f; else Oi[g] = 0.f;
    }
    size_t xoff = (size_t)(xg * 32 + y) * NZ + zm;
    const float* wr = Wr + (size_t)((corner * 32) * 32 + o) * 4096 + m;
    const float* wi = Wi + (size_t)((corner * 32) * 32 + o) * 4096 + m;
    float ar0=0.f, ar1=0.f, ar2=0.f, ar3=0.f;
    float ai0=0.f, ai1=0.f, ai2=0.f, ai3=0.f;
    #pragma unroll 4
    for (int i = 0; i < 32; ++i){
        f4_t w4r = __builtin_nontemporal_load((const f4_t*)(wr + (size_t)i * 131072));
        f4_t w4i = __builtin_nontemporal_load((const f4_t*)(wi + (size_t)i * 131072));
        const float* pxr = Xr + (size_t)i * 17408 + xoff;
        const float* pxi = Xi + (size_t)i * 17408 + xoff;
        float xr0 = pxr[0], xr1 = pxr[1], xr2 = pxr[2], xr3 = pxr[3];
        float xi0 = pxi[0], xi1 = pxi[1], xi2 = pxi[2], xi3 = pxi[3];
        ar0 += w4r.x * xr0 - w4i.x * xi0;  ai0 += w4r.x * xi0 + w4i.x * xr0;
        ar1 += w4r.y * xr1 - w4i.y * xi1;  ai1 += w4r.y * xi1 + w4i.y * xr1;
        ar2 += w4r.z * xr2 - w4i.z * xi2;  ai2 += w4r.z * xi2 + w4i.z * xr2;
        ar3 += w4r.w * xr3 - w4i.w * xi3;  ai3 += w4r.w * xi3 + w4i.w * xr3;
    }
    int g = ((o * 32 + xg) * 32 + y) * NZ + zm;
    Or[g + 0] = ar0; Or[g + 1] = ar1; Or[g + 2] = ar2; Or[g + 3] = ar3;
    Oi[g + 0] = ai0; Oi[g + 1] = ai1; Oi[g + 2] = ai2; Oi[g + 3] = ai3;
}

__global__ void k_ifft_h(const float* __restrict__ Br, const float* __restrict__ Bi,
                         float* __restrict__ Ar, float* __restrict__ Ai){
    __shared__ float ir[544], ii[544];
    __shared__ float ct[32], st[32];
    int b = blockIdx.x, t = threadIdx.x;
    int c = b >> 5, y = b & 31;
    if (t < 32){ float ang = 6.283185307179586477f * (float)t / 32.0f; ct[t] = cosf(ang); st[t] = sinf(ang); }
    for (int j = t; j < 544; j += 256){
        int xk = j / 17, z = j - xk * 17;
        int g = ((c * 32 + xk) * 32 + y) * NZ + z;
        ir[j] = Br[g]; ii[j] = Bi[g];
    }
    __syncthreads();
    for (int idx = t; idx < 544; idx += 256){
        int h = idx / 17, z = idx - h * 17;
        float sr = 0.f, si = 0.f;
        #pragma unroll
        for (int k = 0; k < 32; ++k){
            int a = (k * h) & 31;
            float c2 = ct[a], s2 = st[a];
            float vr = ir[k * 17 + z], vi = ii[k * 17 + z];
            sr += vr * c2 - vi * s2;
            si += vr * s2 + vi * c2;
        }
        int g = ((c * 32 + h) * 32 + y) * NZ + z;
        Ar[g] = sr; Ai[g] = si;
    }
}

__global__ void k_inv(const float* __restrict__ Ar, const float* __restrict__ Ai,
                      float* __restrict__ spec,
                      float* __restrict__ psum, float* __restrict__ psq){
    __shared__ float ir[544], ii[544];
    __shared__ float cr[544], ci[544];
    __shared__ float ct[32], st[32];
    __shared__ float ls[256], lq[256];
    int b = blockIdx.x, t = threadIdx.x;
    if (t < 32){ float ang = 6.283185307179586477f * (float)t / 32.0f; ct[t] = cosf(ang); st[t] = sinf(ang); }
    const float* pr = Ar + b * 544;
    const float* pi = Ai + b * 544;
    for (int j = t; j < 544; j += 256){ ir[j] = pr[j]; ii[j] = pi[j]; }
    __syncthreads();
    for (int idx = t; idx < 544; idx += 256){
        int d = idx / 17, z = idx - d * 17;
        float sr = 0.f, si = 0.f;
        #pragma unroll
        for (int k = 0; k < 32; ++k){
            int a = (k * d) & 31;
            float c2 = ct[a], s2 = st[a];
            float vr = ir[k * 17 + z], vi = ii[k * 17 + z];
            sr += vr * c2 - vi * s2;
            si += vr * s2 + vi * c2;
        }
        cr[idx] = sr; ci[idx] = si;
    }
    __syncthreads();
    const float inv = 1.0f / 32768.0f;
    float s_loc = 0.f, q_loc = 0.f;
    for (int idx = t; idx < 1024; idx += 256){
        int d = idx >> 5, w = idx & 31;
        float s = cr[d * 17 + 0] + ((w & 1) ? -cr[d * 17 + 16] : cr[d * 17 + 16]);
        #pragma unroll
        for (int z = 1; z < 16; ++z){
            int a = (z * w) & 31;
            s += 2.0f * (cr[d * 17 + z] * ct[a] - ci[d * 17 + z] * st[a]);
        }
        s *= inv;
        spec[b * 1024 + idx] = s;
        s_loc += s; q_loc += s * s;
    }
    ls[t] = s_loc; lq[t] = q_loc; __syncthreads();
    for (int off = 128; off > 0; off >>= 1){
        if (t < off){ ls[t] += ls[t + off]; lq[t] += lq[t + off]; }
        __syncthreads();
    }
    if (t == 0){ psum[b] = ls[0]; psq[b] = lq[0]; }
}

__global__ void k_mlp(const float* __restrict__ spec, const float* __restrict__ x,
                      const float* __restrict__ n1g, const float* __restrict__ n1b,
                      const float* __restrict__ psum, const float* __restrict__ psq,
                      const float* __restrict__ w1, const float* __restrict__ b1,
                      const float* __restrict__ w2, const float* __restrict__ b2,
                      float* __restrict__ h2,
                      float* __restrict__ psum2, float* __restrict__ psq2){
    __shared__ float W1[512], W2[512], B1[16], B2[32], GG[32], BB[32];
    __shared__ float ls[256], lq[256];
    int t = threadIdx.x;
    for (int j = t; j < 512; j += 256){ W1[j] = w1[j]; W2[j] = w2[j]; }
    if (t < 16) B1[t] = b1[t];
    if (t < 32){ B2[t] = b2[t]; GG[t] = n1g[t]; BB[t] = n1b[t]; }
    float s0 = 0.f, q0 = 0.f;
    for (int j = t; j < 1024; j += 256){ s0 += psum[j]; q0 += psq[j]; }
    ls[t] = s0; lq[t] = q0; __syncthreads();
    for (int off = 128; off > 0; off >>= 1){
        if (t < off){ ls[t] += ls[t + off]; lq[t] += lq[t + off]; }
        __syncthreads();
    }
    float mu = ls[0] * (1.0f / 1048576.0f);
    float var = lq[0] * (1.0f / 1048576.0f) - mu * mu;
    float rs = rsqrtf(var + 1e-5f);
    __syncthreads();
    int n = blockIdx.x * 256 + t;
    float hv[32];
    #pragma unroll
    for (int c = 0; c < 32; ++c){
        float v = (spec[c * NSP + n] - mu) * rs * GG[c] + BB[c] + x[c * NSP + n];
        hv[c] = geluf(v);
    }
    float u[16];
    #pragma unroll
    for (int o = 0; o < 16; ++o){
        float a = B1[o];
        #pragma unroll
        for (int c = 0; c < 32; ++c) a += W1[o * 32 + c] * hv[c];
        u[o] = geluf(a);
    }
    float s_loc = 0.f, q_loc = 0.f;
    #pragma unroll
    for (int o = 0; o < 32; ++o){
        float a = B2[o];
        #pragma unroll
        for (int c = 0; c < 16; ++c) a += W2[o * 16 + c] * u[c];
        h2[o * NSP + n] = a;
        s_loc += a; q_loc += a * a;
    }
    ls[t] = s_loc; lq[t] = q_loc; __syncthreads();
    for (int off = 128; off > 0; off >>= 1){
        if (t < off){ ls[t] += ls[t + off]; lq[t] += lq[t + off]; }
        __syncthreads();
    }
    if (t == 0){ psum2[blockIdx.x] = ls[0]; psq2[blockIdx.x] = lq[0]; }
}

__global__ void k_qkv(const float* __restrict__ h2,
                      const float* __restrict__ psum2, const float* __restrict__ psq2,
                      const float* __restrict__ tin,
                      const float* __restrict__ tgw, const float* __restrict__ tgb,
                      const float* __restrict__ tbw, const float* __restrict__ tbb,
                      const float* __restrict__ qw, const float* __restrict__ qb,
                      const float* __restrict__ kw, const float* __restrict__ vw,
                      float* __restrict__ h3, float* __restrict__ Q,
                      float* __restrict__ KH, float* __restrict__ VH){
    __shared__ float QW[1024], KW[1024], VW[1024], GA[32], BE[32], QB[32];
    __shared__ float ls[256], lq[256];
    int t = threadIdx.x;
    for (int j = t; j < 1024; j += 256){ QW[j] = qw[j]; KW[j] = kw[j]; VW[j] = vw[j]; }
    if (t < 32) QB[t] = qb[t];
    ls[t] = (t < 128) ? psum2[t] : 0.f;
    lq[t] = (t < 128) ? psq2[t] : 0.f;
    __syncthreads();
    for (int off = 128; off > 0; off >>= 1){
        if (t < off){ ls[t] += ls[t + off]; lq[t] += lq[t + off]; }
        __syncthreads();
    }
    float mu = ls[0] * (1.0f / 1048576.0f);
    float var = lq[0] * (1.0f / 1048576.0f) - mu * mu;
    float rs = rsqrtf(var + 1e-5f);
    __syncthreads();
    if (t < 64){
        int o = t & 31;
        const float* w = (t < 32) ? tgw : tbw;
        const float* bi = (t < 32) ? tgb : tbb;
        float a = bi[o];
        #pragma unroll
        for (int c = 0; c < 32; ++c) a += w[o * 32 + c] * tin[c];
        if (t < 32) GA[o] = a; else BE[o] = a;
    }
    __syncthreads();
    int n = blockIdx.x * 256 + t;
    float hv[32];
    #pragma unroll
    for (int c = 0; c < 32; ++c){
        float v = GA[c] * ((h2[c * NSP + n] - mu) * rs) + BE[c];
        hv[c] = v;
        h3[c * NSP + n] = v;
    }
    #pragma unroll
    for (int o = 0; o < 32; ++o){
        float aq = QB[o], ak = 0.f, av = 0.f;
        #pragma unroll
        for (int c = 0; c < 32; ++c){
            float v = hv[c];
            aq += QW[o * 32 + c] * v;
            ak += KW[o * 32 + c] * v;
            av += VW[o * 32 + c] * v;
        }
        Q[o * NSP + n] = aq;
        KH[o * NSP + n] = ak;
        VH[o * NSP + n] = av;
    }
}

__global__ void k_attn(const float* __restrict__ Q, const float* __restrict__ KH,
                       const float* __restrict__ VH,
                       const float* __restrict__ kb, const float* __restrict__ vb,
                       const float* __restrict__ mk, const float* __restrict__ mv,
                       float* __restrict__ out0){
    __shared__ float KL[3][1024], VL[3][1024];
    int bid = blockIdx.x;
    int swz = (bid & 7) * 128 + (bid >> 3);
    int c = swz >> 5, h_ = swz & 31;
    int t = threadIdx.x;
    #pragma unroll
    for (int p = 0; p < 3; ++p){
        int hh = h_ - 1 + p;
        if ((unsigned)hh < 32u){
            const float* sk = KH + (c * 32 + hh) * 1024;
            const float* sv = VH + (c * 32 + hh) * 1024;
            for (int j = t; j < 1024; j += 256){ KL[p][j] = sk[j]; VL[p][j] = sv[j]; }
        }
    }
    float kbc = kb[c], vbc = vb[c];
    float mkv[5], mvv[5];
    #pragma unroll
    for (int j = 0; j < 5; ++j){ mkv[j] = mk[c * 5 + j]; mvv[j] = mv[c * 5 + j]; }
    float qv[4];
    #pragma unroll
    for (int i = 0; i < 4; ++i) qv[i] = Q[c * NSP + h_ * 1024 + i * 256 + t];
    __syncthreads();
    const float scale = 0.17677669529663688f;
    #pragma unroll
    for (int i = 0; i < 4; ++i){
        int nl = i * 256 + t;
        int d_ = nl >> 5, w_ = nl & 31;
        float q = qv[i];
        float s = 0.f, acc = 0.f;
        #pragma unroll
        for (int j = 0; j < 5; ++j){
            float e = __expf(q * mkv[j] * scale);
            s += e; acc += e * mvv[j];
        }
        int oob = 0;
        #pragma unroll
        for (int p = 0; p < 3; ++p){
            int hh = h_ - 1 + p;
            if ((unsigned)hh >= 32u){ oob += 9; continue; }
            #pragma unroll
            for (int dj = -1; dj <= 1; ++dj){
                int dd = d_ + dj;
                if ((unsigned)dd >= 32u){ oob += 3; continue; }
                int rb = dd * 32;
                #pragma unroll
                for (int dl = -1; dl <= 1; ++dl){
                    int ww = w_ + dl;
                    if ((unsigned)ww < 32u){
                        float k = kbc + KL[p][rb + ww];
                        float v = vbc + VL[p][rb + ww];
                        float e = __expf(q * k * scale);
                        s += e; acc += e * v;
                    } else oob++;
                }
            }
        }
        float eb = __expf(q * kbc * scale);
        s += (float)oob * eb; acc += (float)oob * eb * vbc;
        out0[c * NSP + h_ * 1024 + nl] = acc / s;
    }
}

__global__ void k_gate(const float* __restrict__ h3, const float* __restrict__ out0,
                       const float* __restrict__ x,
                       const float* __restrict__ gw, const float* __restrict__ gb,
                       float* __restrict__ outp, float* __restrict__ mpart){
    __shared__ float GW[2048];
    __shared__ float FT[32 * 264];
    __shared__ float PS[256];
    int t = threadIdx.x;
    for (int j = t; j < 2048; j += 256) GW[j] = gw[j];
    int n = blockIdx.x * 256 + t;
    float hv[32], ov[32];
    #pragma unroll
    for (int c = 0; c < 32; ++c){ hv[c] = h3[c * NSP + n]; ov[c] = out0[c * NSP + n]; }
    __syncthreads();
    #pragma unroll
    for (int c = 0; c < 32; ++c){
        float g = gb[c];
        #pragma unroll
        for (int cc = 0; cc < 32; ++cc){
            g += GW[c * 64 + cc] * hv[cc] + GW[c * 64 + 32 + cc] * ov[cc];
        }
        g = sigmoidf_(g);
        float fin = g * ov[c] + (1.0f - g) * hv[c];
        FT[c * 264 + t] = fin;
        outp[c * NSP + n] = fin + geluf(x[c * NSP + n]);
    }
    __syncthreads();
    {
        int c8 = t >> 3, seg = t & 7;
        float s = 0.f;
        #pragma unroll
        for (int j = 0; j < 32; ++j) s += FT[c8 * 264 + seg * 32 + j];
        PS[t] = s;
    }
    __syncthreads();
    if (t < 32){
        float s = 0.f;
        #pragma unroll
        for (int j = 0; j < 8; ++j) s += PS[t * 8 + j];
        mpart[t * 128 + blockIdx.x] = s;
    }
}

__global__ void k_gru(const float* __restrict__ mpart, const float* __restrict__ pm,
                      const float* __restrict__ wih, const float* __restrict__ whh,
                      const float* __restrict__ bih, const float* __restrict__ bhh,
                      float* __restrict__ outp){
    __shared__ float PS[256];
    __shared__ float m_in[32], gi[96], gh[96];
    int t = threadIdx.x;
    {
        int c = t >> 3, seg = t & 7;
        float s = 0.f;
        #pragma unroll
        for (int j = 0; j < 16; ++j) s += mpart[c * 128 + seg * 16 + j];
        PS[t] = s;
    }
    __syncthreads();
    if (t < 32){
        float a = 0.f;
        #pragma unroll
        for (int j = 0; j < 8; ++j) a += PS[t * 8 + j];
        m_in[t] = a * (1.0f / 32768.0f);
    }
    __syncthreads();
    if (t < 96){
        float a = bih[t], b2 = bhh[t];
        #pragma unroll
        for (int cc = 0; cc < 32; ++cc){
            a += wih[t * 32 + cc] * m_in[cc];
            b2 += whh[t * 32 + cc] * pm[cc];
        }
        gi[t] = a; gh[t] = b2;
    }
    __syncthreads();
    if (t < 32){
        float r = sigmoidf_(gi[t] + gh[t]);
        float z = sigmoidf_(gi[32 + t] + gh[32 + t]);
        float nn = tanhf(gi[64 + t] + r * gh[64 + t]);
        float nm = (1.0f - z) * nn + z * pm[t];
        outp[1048576 + t] = nm;
    }
}

extern "C" void kernel_launch(void* const* d_in, const int* in_sizes, int n_in,
                              void* d_out, int out_size, void* d_ws, size_t ws_size,
                              hipStream_t stream){
    float* ws = (float*)d_ws;
    MegaParams P;
    P.x   = (const float*)d_in[0];
    P.tin = (const float*)d_in[1];
    P.pm  = (const float*)d_in[2];
    P.wsr = (const float*)d_in[3];
    P.wsi = (const float*)d_in[4];
    P.n1g = (const float*)d_in[5];
    P.n1b = (const float*)d_in[6];
    P.mw1 = (const float*)d_in[7];
    P.mb1 = (const float*)d_in[8];
    P.mw2 = (const float*)d_in[9];
    P.mb2 = (const float*)d_in[10];
    P.tgw = (const float*)d_in[11];
    P.tgb = (const float*)d_in[12];
    P.tbw = (const float*)d_in[13];
    P.tbb = (const float*)d_in[14];
    P.qw  = (const float*)d_in[15];
    P.qb  = (const float*)d_in[16];
    P.kw  = (const float*)d_in[17];
    P.kb  = (const float*)d_in[18];
    P.vw  = (const float*)d_in[19];
    P.vb  = (const float*)d_in[20];
    P.mk  = (const float*)d_in[21];
    P.mv  = (const float*)d_in[22];
    P.gw  = (const float*)d_in[23];
    P.gb  = (const float*)d_in[24];
    P.wih = (const float*)d_in[25];
    P.whh = (const float*)d_in[26];
    P.bih = (const float*)d_in[27];
    P.bhh = (const float*)d_in[28];
    P.Ar    = ws + 0;
    P.Ai    = ws + 557056;
    P.Br    = ws + 1114112;
    P.Bi    = ws + 1671168;
    P.spec  = ws + 2228224;
    P.h1    = ws + 3276800;
    P.h2    = ws + 4325376;
    P.h3    = ws + 5373952;
    P.psum  = ws + 6422784;
    P.psq   = ws + 6423808;
    P.psum2 = ws + 6424832;
    P.psq2  = ws + 6425856;
    P.outp  = (float*)d_out;

    void* args[] = { &P };
    hipError_t err = hipLaunchCooperativeKernel((const void*)k_mega, dim3(512), dim3(256), args, 0, stream);
    if (err != hipSuccess){
        // fallback: proven multi-kernel chain
        k_fwd    <<<1024, 256, 0, stream>>>(P.x, P.Br, P.Bi);
        k_fft_h  <<<1024, 256, 0, stream>>>(P.Br, P.Bi, P.Ar, P.Ai);
        k_modemul<<<512, 256, 0, stream>>>(P.Ar, P.Ai, P.wsr, P.wsi, P.Br, P.Bi);
        k_ifft_h <<<1024, 256, 0, stream>>>(P.Br, P.Bi, P.Ar, P.Ai);
        k_inv    <<<1024, 256, 0, stream>>>(P.Ar, P.Ai, P.spec, P.psum, P.psq);
        k_mlp    <<<128, 256, 0, stream>>>(P.spec, P.x, P.n1g, P.n1b, P.psum, P.psq, P.mw1, P.mb1, P.mw2, P.mb2, P.h2, P.psum2, P.psq2);
        k_qkv    <<<128, 256, 0, stream>>>(P.h2, P.psum2, P.psq2, P.tin, P.tgw, P.tgb, P.tbw, P.tbb, P.qw, P.qb, P.kw, P.vw, P.h3, P.Br, P.spec, P.h1);
        k_attn   <<<1024, 256, 0, stream>>>(P.Br, P.spec, P.h1, P.kb, P.vb, P.mk, P.mv, P.Ar);
        k_gate   <<<128, 256, 0, stream>>>(P.h3, P.Ar, P.x, P.gw, P.gb, P.outp, P.h2);
        k_gru    <<<1, 256, 0, stream>>>(P.h2, P.pm, P.wih, P.whh, P.bih, P.bhh, P.outp);
    }
}

// Round 15
// 188.346 us; speedup vs baseline: 4.0426x; 4.0426x over previous
//
#include <hip/hip_runtime.h>
#include <hip/hip_bf16.h>
#include <math.h>

// B=1, C=32, H=D=W=32, N=32768, modes 16^3 (z strictly < 16 kept), KS=3, MEM=5
#define NSP 32768

typedef float f4_t __attribute__((ext_vector_type(4)));

__device__ __forceinline__ float geluf(float x){
    return 0.5f * x * (1.0f + erff(x * 0.70710678118654752f));
}
__device__ __forceinline__ float sigmoidf_(float x){
    return 1.0f / (1.0f + __expf(-x));
}

// ---------------- FFT stages (direct DFT-32, z<16 only) ----------------

// rfft along W (z<16) + fft along D. x: (C,H,D,W). out T1r/i: [c][kd][z][h]. block per (c*32+h)
__global__ void k_fwd(const float* __restrict__ x, float* __restrict__ T1r, float* __restrict__ T1i){
    __shared__ float tile[32*33];
    __shared__ float ar[512], ai[512];
    __shared__ float ct[32], st[32];
    int b = blockIdx.x, t = threadIdx.x;
    if (t < 32){ float ang = 6.283185307179586477f * (float)t / 32.0f; ct[t] = cosf(ang); st[t] = sinf(ang); }
    const float* src = x + b * 1024;
    for (int j = t; j < 1024; j += 256) tile[(j & 31) * 33 + (j >> 5)] = src[j];
    __syncthreads();
    // stage 1: rfft along w -> ar[d][z], z<16
    for (int idx = t; idx < 512; idx += 256){
        int d = idx >> 4, z = idx & 15;
        float sr = 0.f, si = 0.f;
        #pragma unroll
        for (int w = 0; w < 32; ++w){
            int a = (z * w) & 31;
            float v = tile[w * 33 + d];
            sr += v * ct[a];
            si -= v * st[a];
        }
        ar[idx] = sr; ai[idx] = si;     // [d][z]
    }
    __syncthreads();
    // stage 2: fft along d -> write T1[c][kd][z][h]
    int c = b >> 5, h = b & 31;
    for (int idx = t; idx < 512; idx += 256){
        int kd = idx >> 4, z = idx & 15;
        float sr = 0.f, si = 0.f;
        #pragma unroll
        for (int d = 0; d < 32; ++d){
            int a = (kd * d) & 31;
            float c0 = ct[a], s0 = st[a];
            float vr = ar[d * 16 + z], vi = ai[d * 16 + z];
            sr += vr * c0 + vi * s0;    // e^{-i}
            si += vi * c0 - vr * s0;
        }
        int g = (c * 512 + idx) * 32 + h;
        T1r[g] = sr; T1i[g] = si;
    }
}

// fft along H. in T1[c][kd][z][h] (contiguous read). out Ar/Ai: [c][kh][kd][z]. block per (c*32+kd)
__global__ void k_fft_h(const float* __restrict__ T1r, const float* __restrict__ T1i,
                        float* __restrict__ Ar, float* __restrict__ Ai){
    __shared__ float ir[16*33], ii[16*33];   // [z][h] pitch 33 (bank-conflict pad)
    __shared__ float ct[32], st[32];
    int b = blockIdx.x, t = threadIdx.x;
    int c = b >> 5, kd = b & 31;
    if (t < 32){ float ang = 6.283185307179586477f * (float)t / 32.0f; ct[t] = cosf(ang); st[t] = sinf(ang); }
    for (int j = t; j < 512; j += 256){
        int z = j >> 5, h = j & 31;
        ir[z * 33 + h] = T1r[b * 512 + j];
        ii[z * 33 + h] = T1i[b * 512 + j];
    }
    __syncthreads();
    for (int idx = t; idx < 512; idx += 256){
        int kh = idx >> 4, z = idx & 15;
        float sr = 0.f, si = 0.f;
        #pragma unroll
        for (int h = 0; h < 32; ++h){
            int a = (kh * h) & 31;
            float c2 = ct[a], s2 = st[a];
            float vr = ir[z * 33 + h], vi = ii[z * 33 + h];
            sr += vr * c2 + vi * s2;    // e^{-i}
            si += vi * c2 - vr * s2;
        }
        int g = ((c * 32 + kh) * 32 + kd) * 16 + z;
        Ar[g] = sr; Ai[g] = si;
    }
}

// spectral multiply. X: [i][kh][kd][z<16]. W: (4,Ci,Co,16,16,16). Out: [o][kd][kh][z<16].
// block = ((corner*32 + o)*4 + q); thread: 4 consecutive modes. NT weight loads.
__global__ void k_modemul(const float* __restrict__ Xr, const float* __restrict__ Xi,
                          const float* __restrict__ Wr, const float* __restrict__ Wi,
                          float* __restrict__ Or, float* __restrict__ Oi){
    int b = blockIdx.x;
    int q = b & 3;
    int o = (b >> 2) & 31;
    int corner = b >> 7;
    int t = threadIdx.x;
    int m = q * 1024 + t * 4;              // (xm, ym, zm) packed
    int xm = m >> 8, ym = (m >> 4) & 15, zm = m & 15;
    int xg = xm + ((corner & 1) << 4);     // kh
    int y  = ym + ((corner >> 1) << 4);    // kd
    size_t xoff = (size_t)((xg * 32 + y) * 16 + zm);
    const float* wr = Wr + (size_t)((corner * 32) * 32 + o) * 4096 + m;
    const float* wi = Wi + (size_t)((corner * 32) * 32 + o) * 4096 + m;
    float ar0=0.f, ar1=0.f, ar2=0.f, ar3=0.f;
    float ai0=0.f, ai1=0.f, ai2=0.f, ai3=0.f;
    #pragma unroll 4
    for (int i = 0; i < 32; ++i){
        f4_t w4r = __builtin_nontemporal_load((const f4_t*)(wr + (size_t)i * 131072));
        f4_t w4i = __builtin_nontemporal_load((const f4_t*)(wi + (size_t)i * 131072));
        const float* pxr = Xr + (size_t)i * 16384 + xoff;
        const float* pxi = Xi + (size_t)i * 16384 + xoff;
        float xr0 = pxr[0], xr1 = pxr[1], xr2 = pxr[2], xr3 = pxr[3];
        float xi0 = pxi[0], xi1 = pxi[1], xi2 = pxi[2], xi3 = pxi[3];
        ar0 += w4r.x * xr0 - w4i.x * xi0;  ai0 += w4r.x * xi0 + w4i.x * xr0;
        ar1 += w4r.y * xr1 - w4i.y * xi1;  ai1 += w4r.y * xi1 + w4i.y * xr1;
        ar2 += w4r.z * xr2 - w4i.z * xi2;  ai2 += w4r.z * xi2 + w4i.z * xr2;
        ar3 += w4r.w * xr3 - w4i.w * xi3;  ai3 += w4r.w * xi3 + w4i.w * xr3;
    }
    int g = ((o * 32 + y) * 32 + xg) * 16 + zm;   // [o][kd][kh][z]
    Or[g + 0] = ar0; Or[g + 1] = ar1; Or[g + 2] = ar2; Or[g + 3] = ar3;
    Oi[g + 0] = ai0; Oi[g + 1] = ai1; Oi[g + 2] = ai2; Oi[g + 3] = ai3;
}

// inverse fft along H. in [o][kd][kh][z] (contiguous read). out [o][h][kd][z]. block per (o*32+kd)
__global__ void k_ifft_h(const float* __restrict__ Br, const float* __restrict__ Bi,
                         float* __restrict__ Ar, float* __restrict__ Ai){
    __shared__ float ir[512], ii[512];   // [kh][z]
    __shared__ float ct[32], st[32];
    int b = blockIdx.x, t = threadIdx.x;
    int o = b >> 5, y = b & 31;
    if (t < 32){ float ang = 6.283185307179586477f * (float)t / 32.0f; ct[t] = cosf(ang); st[t] = sinf(ang); }
    for (int j = t; j < 512; j += 256){ ir[j] = Br[b * 512 + j]; ii[j] = Bi[b * 512 + j]; }
    __syncthreads();
    for (int idx = t; idx < 512; idx += 256){
        int h = idx >> 4, z = idx & 15;
        float sr = 0.f, si = 0.f;
        #pragma unroll
        for (int k = 0; k < 32; ++k){
            int a = (k * h) & 31;
            float c2 = ct[a], s2 = st[a];
            float vr = ir[k * 16 + z], vi = ii[k * 16 + z];
            sr += vr * c2 - vi * s2;    // e^{+i}
            si += vr * s2 + vi * c2;
        }
        int g = ((o * 32 + h) * 32 + y) * 16 + z;
        Ar[g] = sr; Ai[g] = si;
    }
}

// inverse fft along D + irfft along W (z=16 term = 0) + GN1 partials. in [o][h][kd][z] contiguous.
__global__ void k_inv(const float* __restrict__ Ar, const float* __restrict__ Ai,
                      float* __restrict__ spec,
                      float* __restrict__ psum, float* __restrict__ psq){
    __shared__ float ir[512], ii[512];   // [kd][z]
    __shared__ float cr[512], ci[512];   // [d][z]
    __shared__ float ct[32], st[32];
    __shared__ float ls[256], lq[256];
    int b = blockIdx.x, t = threadIdx.x;
    if (t < 32){ float ang = 6.283185307179586477f * (float)t / 32.0f; ct[t] = cosf(ang); st[t] = sinf(ang); }
    for (int j = t; j < 512; j += 256){ ir[j] = Ar[b * 512 + j]; ii[j] = Ai[b * 512 + j]; }
    __syncthreads();
    for (int idx = t; idx < 512; idx += 256){
        int d = idx >> 4, z = idx & 15;
        float sr = 0.f, si = 0.f;
        #pragma unroll
        for (int k = 0; k < 32; ++k){
            int a = (k * d) & 31;
            float c2 = ct[a], s2 = st[a];
            float vr = ir[k * 16 + z], vi = ii[k * 16 + z];
            sr += vr * c2 - vi * s2;
            si += vr * s2 + vi * c2;
        }
        cr[idx] = sr; ci[idx] = si;
    }
    __syncthreads();
    const float inv = 1.0f / 32768.0f;
    float s_loc = 0.f, q_loc = 0.f;
    for (int idx = t; idx < 1024; idx += 256){
        int d = idx >> 5, w = idx & 31;
        float s = cr[d * 16 + 0];
        #pragma unroll
        for (int z = 1; z < 16; ++z){
            int a = (z * w) & 31;
            s += 2.0f * (cr[d * 16 + z] * ct[a] - ci[d * 16 + z] * st[a]);
        }
        s *= inv;
        spec[b * 1024 + idx] = s;
        s_loc += s; q_loc += s * s;
    }
    ls[t] = s_loc; lq[t] = q_loc; __syncthreads();
    for (int off = 128; off > 0; off >>= 1){
        if (t < off){ ls[t] += ls[t + off]; lq[t] += lq[t + off]; }
        __syncthreads();
    }
    if (t == 0){ psum[b] = ls[0]; psq[b] = lq[0]; }
}

// ---------------- elementwise chain (unchanged from round 12) ----------------

__global__ void k_mlp(const float* __restrict__ spec, const float* __restrict__ x,
                      const float* __restrict__ n1g, const float* __restrict__ n1b,
                      const float* __restrict__ psum, const float* __restrict__ psq,
                      const float* __restrict__ w1, const float* __restrict__ b1,
                      const float* __restrict__ w2, const float* __restrict__ b2,
                      float* __restrict__ h2,
                      float* __restrict__ psum2, float* __restrict__ psq2){
    __shared__ float W1[512], W2[512], B1[16], B2[32], GG[32], BB[32];
    __shared__ float ls[256], lq[256];
    int t = threadIdx.x;
    for (int j = t; j < 512; j += 256){ W1[j] = w1[j]; W2[j] = w2[j]; }
    if (t < 16) B1[t] = b1[t];
    if (t < 32){ B2[t] = b2[t]; GG[t] = n1g[t]; BB[t] = n1b[t]; }
    float s0 = 0.f, q0 = 0.f;
    for (int j = t; j < 1024; j += 256){ s0 += psum[j]; q0 += psq[j]; }
    ls[t] = s0; lq[t] = q0; __syncthreads();
    for (int off = 128; off > 0; off >>= 1){
        if (t < off){ ls[t] += ls[t + off]; lq[t] += lq[t + off]; }
        __syncthreads();
    }
    float mu = ls[0] * (1.0f / 1048576.0f);
    float var = lq[0] * (1.0f / 1048576.0f) - mu * mu;
    float rs = rsqrtf(var + 1e-5f);
    __syncthreads();
    int n = blockIdx.x * 256 + t;
    float hv[32];
    #pragma unroll
    for (int c = 0; c < 32; ++c){
        float v = (spec[c * NSP + n] - mu) * rs * GG[c] + BB[c] + x[c * NSP + n];
        hv[c] = geluf(v);
    }
    float u[16];
    #pragma unroll
    for (int o = 0; o < 16; ++o){
        float a = B1[o];
        #pragma unroll
        for (int c = 0; c < 32; ++c) a += W1[o * 32 + c] * hv[c];
        u[o] = geluf(a);
    }
    float s_loc = 0.f, q_loc = 0.f;
    #pragma unroll
    for (int o = 0; o < 32; ++o){
        float a = B2[o];
        #pragma unroll
        for (int c = 0; c < 16; ++c) a += W2[o * 16 + c] * u[c];
        h2[o * NSP + n] = a;
        s_loc += a; q_loc += a * a;
    }
    ls[t] = s_loc; lq[t] = q_loc; __syncthreads();
    for (int off = 128; off > 0; off >>= 1){
        if (t < off){ ls[t] += ls[t + off]; lq[t] += lq[t + off]; }
        __syncthreads();
    }
    if (t == 0){ psum2[blockIdx.x] = ls[0]; psq2[blockIdx.x] = lq[0]; }
}

__global__ void k_qkv(const float* __restrict__ h2,
                      const float* __restrict__ psum2, const float* __restrict__ psq2,
                      const float* __restrict__ tin,
                      const float* __restrict__ tgw, const float* __restrict__ tgb,
                      const float* __restrict__ tbw, const float* __restrict__ tbb,
                      const float* __restrict__ qw, const float* __restrict__ qb,
                      const float* __restrict__ kw, const float* __restrict__ vw,
                      float* __restrict__ h3, float* __restrict__ Q,
                      float* __restrict__ KH, float* __restrict__ VH){
    __shared__ float QW[1024], KW[1024], VW[1024], GA[32], BE[32], QB[32];
    __shared__ float ls[256], lq[256];
    int t = threadIdx.x;
    for (int j = t; j < 1024; j += 256){ QW[j] = qw[j]; KW[j] = kw[j]; VW[j] = vw[j]; }
    if (t < 32) QB[t] = qb[t];
    ls[t] = (t < 128) ? psum2[t] : 0.f;
    lq[t] = (t < 128) ? psq2[t] : 0.f;
    __syncthreads();
    for (int off = 128; off > 0; off >>= 1){
        if (t < off){ ls[t] += ls[t + off]; lq[t] += lq[t + off]; }
        __syncthreads();
    }
    float mu = ls[0] * (1.0f / 1048576.0f);
    float var = lq[0] * (1.0f / 1048576.0f) - mu * mu;
    float rs = rsqrtf(var + 1e-5f);
    __syncthreads();
    if (t < 64){
        int o = t & 31;
        const float* w = (t < 32) ? tgw : tbw;
        const float* bi = (t < 32) ? tgb : tbb;
        float a = bi[o];
        #pragma unroll
        for (int c = 0; c < 32; ++c) a += w[o * 32 + c] * tin[c];
        if (t < 32) GA[o] = a; else BE[o] = a;
    }
    __syncthreads();
    int n = blockIdx.x * 256 + t;
    float hv[32];
    #pragma unroll
    for (int c = 0; c < 32; ++c){
        float v = GA[c] * ((h2[c * NSP + n] - mu) * rs) + BE[c];
        hv[c] = v;
        h3[c * NSP + n] = v;
    }
    #pragma unroll
    for (int o = 0; o < 32; ++o){
        float aq = QB[o], ak = 0.f, av = 0.f;
        #pragma unroll
        for (int c = 0; c < 32; ++c){
            float v = hv[c];
            aq += QW[o * 32 + c] * v;
            ak += KW[o * 32 + c] * v;
            av += VW[o * 32 + c] * v;
        }
        Q[o * NSP + n] = aq;
        KH[o * NSP + n] = ak;
        VH[o * NSP + n] = av;
    }
}

__global__ void k_attn(const float* __restrict__ Q, const float* __restrict__ KH,
                       const float* __restrict__ VH,
                       const float* __restrict__ kb, const float* __restrict__ vb,
                       const float* __restrict__ mk, const float* __restrict__ mv,
                       float* __restrict__ out0){
    __shared__ float KL[3][1024], VL[3][1024];
    int bid = blockIdx.x;
    int swz = (bid & 7) * 128 + (bid >> 3);
    int c = swz >> 5, h_ = swz & 31;
    int t = threadIdx.x;
    #pragma unroll
    for (int p = 0; p < 3; ++p){
        int hh = h_ - 1 + p;
        if ((unsigned)hh < 32u){
            const float* sk = KH + (c * 32 + hh) * 1024;
            const float* sv = VH + (c * 32 + hh) * 1024;
            for (int j = t; j < 1024; j += 256){ KL[p][j] = sk[j]; VL[p][j] = sv[j]; }
        }
    }
    float kbc = kb[c], vbc = vb[c];
    float mkv[5], mvv[5];
    #pragma unroll
    for (int j = 0; j < 5; ++j){ mkv[j] = mk[c * 5 + j]; mvv[j] = mv[c * 5 + j]; }
    float qv[4];
    #pragma unroll
    for (int i = 0; i < 4; ++i) qv[i] = Q[c * NSP + h_ * 1024 + i * 256 + t];
    __syncthreads();
    const float scale = 0.17677669529663688f;
    #pragma unroll
    for (int i = 0; i < 4; ++i){
        int nl = i * 256 + t;
        int d_ = nl >> 5, w_ = nl & 31;
        float q = qv[i];
        float s = 0.f, acc = 0.f;
        #pragma unroll
        for (int j = 0; j < 5; ++j){
            float e = __expf(q * mkv[j] * scale);
            s += e; acc += e * mvv[j];
        }
        int oob = 0;
        #pragma unroll
        for (int p = 0; p < 3; ++p){
            int hh = h_ - 1 + p;
            if ((unsigned)hh >= 32u){ oob += 9; continue; }
            #pragma unroll
            for (int dj = -1; dj <= 1; ++dj){
                int dd = d_ + dj;
                if ((unsigned)dd >= 32u){ oob += 3; continue; }
                int rb = dd * 32;
                #pragma unroll
                for (int dl = -1; dl <= 1; ++dl){
                    int ww = w_ + dl;
                    if ((unsigned)ww < 32u){
                        float k = kbc + KL[p][rb + ww];
                        float v = vbc + VL[p][rb + ww];
                        float e = __expf(q * k * scale);
                        s += e; acc += e * v;
                    } else oob++;
                }
            }
        }
        float eb = __expf(q * kbc * scale);
        s += (float)oob * eb; acc += (float)oob * eb * vbc;
        out0[c * NSP + h_ * 1024 + nl] = acc / s;
    }
}

__global__ void k_gate(const float* __restrict__ h3, const float* __restrict__ out0,
                       const float* __restrict__ x,
                       const float* __restrict__ gw, const float* __restrict__ gb,
                       float* __restrict__ outp, float* __restrict__ mpart){
    __shared__ float GW[2048];
    __shared__ float FT[32 * 264];
    __shared__ float PS[256];
    int t = threadIdx.x;
    for (int j = t; j < 2048; j += 256) GW[j] = gw[j];
    int n = blockIdx.x * 256 + t;
    float hv[32], ov[32];
    #pragma unroll
    for (int c = 0; c < 32; ++c){ hv[c] = h3[c * NSP + n]; ov[c] = out0[c * NSP + n]; }
    __syncthreads();
    #pragma unroll
    for (int c = 0; c < 32; ++c){
        float g = gb[c];
        #pragma unroll
        for (int cc = 0; cc < 32; ++cc){
            g += GW[c * 64 + cc] * hv[cc] + GW[c * 64 + 32 + cc] * ov[cc];
        }
        g = sigmoidf_(g);
        float fin = g * ov[c] + (1.0f - g) * hv[c];
        FT[c * 264 + t] = fin;
        outp[c * NSP + n] = fin + geluf(x[c * NSP + n]);
    }
    __syncthreads();
    {
        int c8 = t >> 3, seg = t & 7;
        float s = 0.f;
        #pragma unroll
        for (int j = 0; j < 32; ++j) s += FT[c8 * 264 + seg * 32 + j];
        PS[t] = s;
    }
    __syncthreads();
    if (t < 32){
        float s = 0.f;
        #pragma unroll
        for (int j = 0; j < 8; ++j) s += PS[t * 8 + j];
        mpart[t * 128 + blockIdx.x] = s;
    }
}

__global__ void k_gru(const float* __restrict__ mpart, const float* __restrict__ pm,
                      const float* __restrict__ wih, const float* __restrict__ whh,
                      const float* __restrict__ bih, const float* __restrict__ bhh,
                      float* __restrict__ outp){
    __shared__ float PS[256];
    __shared__ float m_in[32], gi[96], gh[96];
    int t = threadIdx.x;
    {
        int c = t >> 3, seg = t & 7;
        float s = 0.f;
        #pragma unroll
        for (int j = 0; j < 16; ++j) s += mpart[c * 128 + seg * 16 + j];
        PS[t] = s;
    }
    __syncthreads();
    if (t < 32){
        float a = 0.f;
        #pragma unroll
        for (int j = 0; j < 8; ++j) a += PS[t * 8 + j];
        m_in[t] = a * (1.0f / 32768.0f);
    }
    __syncthreads();
    if (t < 96){
        float a = bih[t], b2 = bhh[t];
        #pragma unroll
        for (int cc = 0; cc < 32; ++cc){
            a += wih[t * 32 + cc] * m_in[cc];
            b2 += whh[t * 32 + cc] * pm[cc];
        }
        gi[t] = a; gh[t] = b2;
    }
    __syncthreads();
    if (t < 32){
        float r = sigmoidf_(gi[t] + gh[t]);
        float z = sigmoidf_(gi[32 + t] + gh[32 + t]);
        float nn = tanhf(gi[64 + t] + r * gh[64 + t]);
        float nm = (1.0f - z) * nn + z * pm[t];
        outp[1048576 + t] = nm;
    }
}

extern "C" void kernel_launch(void* const* d_in, const int* in_sizes, int n_in,
                              void* d_out, int out_size, void* d_ws, size_t ws_size,
                              hipStream_t stream){
    const float* x   = (const float*)d_in[0];
    const float* tin = (const float*)d_in[1];
    const float* pm  = (const float*)d_in[2];
    const float* wsr = (const float*)d_in[3];
    const float* wsi = (const float*)d_in[4];
    const float* n1g = (const float*)d_in[5];
    const float* n1b = (const float*)d_in[6];
    const float* mw1 = (const float*)d_in[7];
    const float* mb1 = (const float*)d_in[8];
    const float* mw2 = (const float*)d_in[9];
    const float* mb2 = (const float*)d_in[10];
    const float* tgw = (const float*)d_in[11];
    const float* tgb = (const float*)d_in[12];
    const float* tbw = (const float*)d_in[13];
    const float* tbb = (const float*)d_in[14];
    const float* qw  = (const float*)d_in[15];
    const float* qb  = (const float*)d_in[16];
    const float* kw  = (const float*)d_in[17];
    const float* kb  = (const float*)d_in[18];
    const float* vw  = (const float*)d_in[19];
    const float* vb  = (const float*)d_in[20];
    const float* mk  = (const float*)d_in[21];
    const float* mv  = (const float*)d_in[22];
    const float* gw  = (const float*)d_in[23];
    const float* gb  = (const float*)d_in[24];
    const float* wih = (const float*)d_in[25];
    const float* whh = (const float*)d_in[26];
    const float* bih = (const float*)d_in[27];
    const float* bhh = (const float*)d_in[28];

    float* ws = (float*)d_ws;
    float* Ar    = ws + 0;        // 524288 used (slot 557056)
    float* Ai    = ws + 557056;
    float* Br    = ws + 1114112;
    float* Bi    = ws + 1671168;
    float* spec  = ws + 2228224;  // 1048576
    float* h1    = ws + 3276800;  // 1048576 (VH)
    float* h2    = ws + 4325376;  // 1048576
    float* h3    = ws + 5373952;  // 1048576
    float* psum  = ws + 6422784;  // 1024
    float* psq   = ws + 6423808;  // 1024
    float* psum2 = ws + 6424832;  // 1024
    float* psq2  = ws + 6425856;  // 1024
    // aliases (free by the time they're used)
    float* Qb    = Br;    // free after k_inv
    float* KHb   = spec;  // free after k_mlp
    float* VHb   = h1;
    float* out0  = Ar;    // free after k_inv
    float* mpart = h2;    // 32*128, free after k_qkv

    float* outp = (float*)d_out;

    k_fwd    <<<1024, 256, 0, stream>>>(x, Br, Bi);            // T1 in Br/Bi
    k_fft_h  <<<1024, 256, 0, stream>>>(Br, Bi, Ar, Ai);
    k_modemul<<<512, 256, 0, stream>>>(Ar, Ai, wsr, wsi, Br, Bi);
    k_ifft_h <<<1024, 256, 0, stream>>>(Br, Bi, Ar, Ai);
    k_inv    <<<1024, 256, 0, stream>>>(Ar, Ai, spec, psum, psq);
    k_mlp    <<<128, 256, 0, stream>>>(spec, x, n1g, n1b, psum, psq, mw1, mb1, mw2, mb2, h2, psum2, psq2);
    k_qkv    <<<128, 256, 0, stream>>>(h2, psum2, psq2, tin, tgw, tgb, tbw, tbb, qw, qb, kw, vw, h3, Qb, KHb, VHb);
    k_attn   <<<1024, 256, 0, stream>>>(Qb, KHb, VHb, kb, vb, mk, mv, out0);
    k_gate   <<<128, 256, 0, stream>>>(h3, out0, x, gw, gb, outp, mpart);
    k_gru    <<<1, 256, 0, stream>>>(mpart, pm, wih, whh, bih, bhh, outp);
}

// Round 16
// 186.839 us; speedup vs baseline: 4.0752x; 1.0081x over previous
//
#include <hip/hip_runtime.h>
#include <hip/hip_bf16.h>
#include <math.h>

// B=1, C=32, H=D=W=32, N=32768, modes 16^3 (z strictly < 16 kept), KS=3, MEM=5
#define NSP 32768

typedef float f4_t __attribute__((ext_vector_type(4)));

__device__ __forceinline__ float geluf(float x){
    return 0.5f * x * (1.0f + erff(x * 0.70710678118654752f));
}
__device__ __forceinline__ float sigmoidf_(float x){
    return 1.0f / (1.0f + __expf(-x));
}

// ---------------- FFT stages (direct DFT-32, z<16 only) ----------------

// rfft along W (z<16) + fft along D. x: (C,H,D,W). out T1r/i: [c][kd][z][h]. block per (c*32+h)
__global__ void k_fwd(const float* __restrict__ x, float* __restrict__ T1r, float* __restrict__ T1i){
    __shared__ float tile[32*33];
    __shared__ float ar[512], ai[512];
    __shared__ float ct[32], st[32];
    int b = blockIdx.x, t = threadIdx.x;
    if (t < 32){ float ang = 6.283185307179586477f * (float)t / 32.0f; ct[t] = cosf(ang); st[t] = sinf(ang); }
    const float* src = x + b * 1024;
    for (int j = t; j < 1024; j += 256) tile[(j & 31) * 33 + (j >> 5)] = src[j];
    __syncthreads();
    for (int idx = t; idx < 512; idx += 256){
        int d = idx >> 4, z = idx & 15;
        float sr = 0.f, si = 0.f;
        #pragma unroll
        for (int w = 0; w < 32; ++w){
            int a = (z * w) & 31;
            float v = tile[w * 33 + d];
            sr += v * ct[a];
            si -= v * st[a];
        }
        ar[idx] = sr; ai[idx] = si;     // [d][z]
    }
    __syncthreads();
    int c = b >> 5, h = b & 31;
    for (int idx = t; idx < 512; idx += 256){
        int kd = idx >> 4, z = idx & 15;
        float sr = 0.f, si = 0.f;
        #pragma unroll
        for (int d = 0; d < 32; ++d){
            int a = (kd * d) & 31;
            float c0 = ct[a], s0 = st[a];
            float vr = ar[d * 16 + z], vi = ai[d * 16 + z];
            sr += vr * c0 + vi * s0;    // e^{-i}
            si += vi * c0 - vr * s0;
        }
        int g = (c * 512 + idx) * 32 + h;
        T1r[g] = sr; T1i[g] = si;
    }
}

// fft along H. in T1[c][kd][z][h] (contiguous read). out Ar/Ai: [c][kh][kd][z]. block per (c*32+kd)
__global__ void k_fft_h(const float* __restrict__ T1r, const float* __restrict__ T1i,
                        float* __restrict__ Ar, float* __restrict__ Ai){
    __shared__ float ir[16*33], ii[16*33];   // [z][h] pitch 33
    __shared__ float ct[32], st[32];
    int b = blockIdx.x, t = threadIdx.x;
    int c = b >> 5, kd = b & 31;
    if (t < 32){ float ang = 6.283185307179586477f * (float)t / 32.0f; ct[t] = cosf(ang); st[t] = sinf(ang); }
    for (int j = t; j < 512; j += 256){
        int z = j >> 5, h = j & 31;
        ir[z * 33 + h] = T1r[b * 512 + j];
        ii[z * 33 + h] = T1i[b * 512 + j];
    }
    __syncthreads();
    for (int idx = t; idx < 512; idx += 256){
        int kh = idx >> 4, z = idx & 15;
        float sr = 0.f, si = 0.f;
        #pragma unroll
        for (int h = 0; h < 32; ++h){
            int a = (kh * h) & 31;
            float c2 = ct[a], s2 = st[a];
            float vr = ir[z * 33 + h], vi = ii[z * 33 + h];
            sr += vr * c2 + vi * s2;    // e^{-i}
            si += vi * c2 - vr * s2;
        }
        int g = ((c * 32 + kh) * 32 + kd) * 16 + z;
        Ar[g] = sr; Ai[g] = si;
    }
}

// spectral multiply, i-split for 2x TLP. X: [i][kh][kd][z<16]. W: (4,Ci,Co,16,16,16).
// grid 1024 = (ih, corner, o, q). ih=0 -> P0 (Br/Bi); ih=1 -> P1 (Cr/Ci). out layout [o][kd][kh][z].
__global__ void k_modemul(const float* __restrict__ Xr, const float* __restrict__ Xi,
                          const float* __restrict__ Wr, const float* __restrict__ Wi,
                          float* __restrict__ P0r, float* __restrict__ P0i,
                          float* __restrict__ P1r, float* __restrict__ P1i){
    int b = blockIdx.x;
    int ih = b >> 9;               // 0 or 1
    int rem = b & 511;
    int q = rem & 3;
    int o = (rem >> 2) & 31;
    int corner = rem >> 7;
    int t = threadIdx.x;
    int m = q * 1024 + t * 4;
    int xm = m >> 8, ym = (m >> 4) & 15, zm = m & 15;
    int xg = xm + ((corner & 1) << 4);     // kh
    int y  = ym + ((corner >> 1) << 4);    // kd
    size_t xoff = (size_t)((xg * 32 + y) * 16 + zm) + (size_t)(ih * 16) * 16384;
    const float* wr = Wr + (size_t)((corner * 32 + ih * 16) * 32 + o) * 4096 + m;
    const float* wi = Wi + (size_t)((corner * 32 + ih * 16) * 32 + o) * 4096 + m;
    float ar0=0.f, ar1=0.f, ar2=0.f, ar3=0.f;
    float ai0=0.f, ai1=0.f, ai2=0.f, ai3=0.f;
    #pragma unroll 4
    for (int i = 0; i < 16; ++i){
        f4_t w4r = __builtin_nontemporal_load((const f4_t*)(wr + (size_t)i * 131072));
        f4_t w4i = __builtin_nontemporal_load((const f4_t*)(wi + (size_t)i * 131072));
        const float* pxr = Xr + (size_t)i * 16384 + xoff;
        const float* pxi = Xi + (size_t)i * 16384 + xoff;
        float xr0 = pxr[0], xr1 = pxr[1], xr2 = pxr[2], xr3 = pxr[3];
        float xi0 = pxi[0], xi1 = pxi[1], xi2 = pxi[2], xi3 = pxi[3];
        ar0 += w4r.x * xr0 - w4i.x * xi0;  ai0 += w4r.x * xi0 + w4i.x * xr0;
        ar1 += w4r.y * xr1 - w4i.y * xi1;  ai1 += w4r.y * xi1 + w4i.y * xr1;
        ar2 += w4r.z * xr2 - w4i.z * xi2;  ai2 += w4r.z * xi2 + w4i.z * xr2;
        ar3 += w4r.w * xr3 - w4i.w * xi3;  ai3 += w4r.w * xi3 + w4i.w * xr3;
    }
    int g = ((o * 32 + y) * 32 + xg) * 16 + zm;   // [o][kd][kh][z]
    float* Orp = ih ? P1r : P0r;
    float* Oip = ih ? P1i : P0i;
    Orp[g + 0] = ar0; Orp[g + 1] = ar1; Orp[g + 2] = ar2; Orp[g + 3] = ar3;
    Oip[g + 0] = ai0; Oip[g + 1] = ai1; Oip[g + 2] = ai2; Oip[g + 3] = ai3;
}

// inverse fft along H. in P0+P1 [o][kd][kh][z] (contiguous reads, summed). out [o][h][kd][z].
__global__ void k_ifft_h(const float* __restrict__ P0r, const float* __restrict__ P0i,
                         const float* __restrict__ P1r, const float* __restrict__ P1i,
                         float* __restrict__ Ar, float* __restrict__ Ai){
    __shared__ float ir[512], ii[512];   // [kh][z]
    __shared__ float ct[32], st[32];
    int b = blockIdx.x, t = threadIdx.x;
    int o = b >> 5, y = b & 31;
    if (t < 32){ float ang = 6.283185307179586477f * (float)t / 32.0f; ct[t] = cosf(ang); st[t] = sinf(ang); }
    for (int j = t; j < 512; j += 256){
        ir[j] = P0r[b * 512 + j] + P1r[b * 512 + j];
        ii[j] = P0i[b * 512 + j] + P1i[b * 512 + j];
    }
    __syncthreads();
    for (int idx = t; idx < 512; idx += 256){
        int h = idx >> 4, z = idx & 15;
        float sr = 0.f, si = 0.f;
        #pragma unroll
        for (int k = 0; k < 32; ++k){
            int a = (k * h) & 31;
            float c2 = ct[a], s2 = st[a];
            float vr = ir[k * 16 + z], vi = ii[k * 16 + z];
            sr += vr * c2 - vi * s2;    // e^{+i}
            si += vr * s2 + vi * c2;
        }
        int g = ((o * 32 + h) * 32 + y) * 16 + z;
        Ar[g] = sr; Ai[g] = si;
    }
}

// inverse fft along D + irfft along W + GN1 partials. in [o][h][kd][z] contiguous.
__global__ void k_inv(const float* __restrict__ Ar, const float* __restrict__ Ai,
                      float* __restrict__ spec,
                      float* __restrict__ psum, float* __restrict__ psq){
    __shared__ float ir[512], ii[512];   // [kd][z]
    __shared__ float cr[512], ci[512];   // [d][z]
    __shared__ float ct[32], st[32];
    __shared__ float ls[256], lq[256];
    int b = blockIdx.x, t = threadIdx.x;
    if (t < 32){ float ang = 6.283185307179586477f * (float)t / 32.0f; ct[t] = cosf(ang); st[t] = sinf(ang); }
    for (int j = t; j < 512; j += 256){ ir[j] = Ar[b * 512 + j]; ii[j] = Ai[b * 512 + j]; }
    __syncthreads();
    for (int idx = t; idx < 512; idx += 256){
        int d = idx >> 4, z = idx & 15;
        float sr = 0.f, si = 0.f;
        #pragma unroll
        for (int k = 0; k < 32; ++k){
            int a = (k * d) & 31;
            float c2 = ct[a], s2 = st[a];
            float vr = ir[k * 16 + z], vi = ii[k * 16 + z];
            sr += vr * c2 - vi * s2;
            si += vr * s2 + vi * c2;
        }
        cr[idx] = sr; ci[idx] = si;
    }
    __syncthreads();
    const float inv = 1.0f / 32768.0f;
    float s_loc = 0.f, q_loc = 0.f;
    for (int idx = t; idx < 1024; idx += 256){
        int d = idx >> 5, w = idx & 31;
        float s = cr[d * 16 + 0];
        #pragma unroll
        for (int z = 1; z < 16; ++z){
            int a = (z * w) & 31;
            s += 2.0f * (cr[d * 16 + z] * ct[a] - ci[d * 16 + z] * st[a]);
        }
        s *= inv;
        spec[b * 1024 + idx] = s;
        s_loc += s; q_loc += s * s;
    }
    ls[t] = s_loc; lq[t] = q_loc; __syncthreads();
    for (int off = 128; off > 0; off >>= 1){
        if (t < off){ ls[t] += ls[t + off]; lq[t] += lq[t + off]; }
        __syncthreads();
    }
    if (t == 0){ psum[b] = ls[0]; psq[b] = lq[0]; }
}

// ---------------- elementwise chain (unchanged) ----------------

__global__ void k_mlp(const float* __restrict__ spec, const float* __restrict__ x,
                      const float* __restrict__ n1g, const float* __restrict__ n1b,
                      const float* __restrict__ psum, const float* __restrict__ psq,
                      const float* __restrict__ w1, const float* __restrict__ b1,
                      const float* __restrict__ w2, const float* __restrict__ b2,
                      float* __restrict__ h2,
                      float* __restrict__ psum2, float* __restrict__ psq2){
    __shared__ float W1[512], W2[512], B1[16], B2[32], GG[32], BB[32];
    __shared__ float ls[256], lq[256];
    int t = threadIdx.x;
    for (int j = t; j < 512; j += 256){ W1[j] = w1[j]; W2[j] = w2[j]; }
    if (t < 16) B1[t] = b1[t];
    if (t < 32){ B2[t] = b2[t]; GG[t] = n1g[t]; BB[t] = n1b[t]; }
    float s0 = 0.f, q0 = 0.f;
    for (int j = t; j < 1024; j += 256){ s0 += psum[j]; q0 += psq[j]; }
    ls[t] = s0; lq[t] = q0; __syncthreads();
    for (int off = 128; off > 0; off >>= 1){
        if (t < off){ ls[t] += ls[t + off]; lq[t] += lq[t + off]; }
        __syncthreads();
    }
    float mu = ls[0] * (1.0f / 1048576.0f);
    float var = lq[0] * (1.0f / 1048576.0f) - mu * mu;
    float rs = rsqrtf(var + 1e-5f);
    __syncthreads();
    int n = blockIdx.x * 256 + t;
    float hv[32];
    #pragma unroll
    for (int c = 0; c < 32; ++c){
        float v = (spec[c * NSP + n] - mu) * rs * GG[c] + BB[c] + x[c * NSP + n];
        hv[c] = geluf(v);
    }
    float u[16];
    #pragma unroll
    for (int o = 0; o < 16; ++o){
        float a = B1[o];
        #pragma unroll
        for (int c = 0; c < 32; ++c) a += W1[o * 32 + c] * hv[c];
        u[o] = geluf(a);
    }
    float s_loc = 0.f, q_loc = 0.f;
    #pragma unroll
    for (int o = 0; o < 32; ++o){
        float a = B2[o];
        #pragma unroll
        for (int c = 0; c < 16; ++c) a += W2[o * 16 + c] * u[c];
        h2[o * NSP + n] = a;
        s_loc += a; q_loc += a * a;
    }
    ls[t] = s_loc; lq[t] = q_loc; __syncthreads();
    for (int off = 128; off > 0; off >>= 1){
        if (t < off){ ls[t] += ls[t + off]; lq[t] += lq[t + off]; }
        __syncthreads();
    }
    if (t == 0){ psum2[blockIdx.x] = ls[0]; psq2[blockIdx.x] = lq[0]; }
}

__global__ void k_qkv(const float* __restrict__ h2,
                      const float* __restrict__ psum2, const float* __restrict__ psq2,
                      const float* __restrict__ tin,
                      const float* __restrict__ tgw, const float* __restrict__ tgb,
                      const float* __restrict__ tbw, const float* __restrict__ tbb,
                      const float* __restrict__ qw, const float* __restrict__ qb,
                      const float* __restrict__ kw, const float* __restrict__ vw,
                      float* __restrict__ h3, float* __restrict__ Q,
                      float* __restrict__ KH, float* __restrict__ VH){
    __shared__ float QW[1024], KW[1024], VW[1024], GA[32], BE[32], QB[32];
    __shared__ float ls[256], lq[256];
    int t = threadIdx.x;
    for (int j = t; j < 1024; j += 256){ QW[j] = qw[j]; KW[j] = kw[j]; VW[j] = vw[j]; }
    if (t < 32) QB[t] = qb[t];
    ls[t] = (t < 128) ? psum2[t] : 0.f;
    lq[t] = (t < 128) ? psq2[t] : 0.f;
    __syncthreads();
    for (int off = 128; off > 0; off >>= 1){
        if (t < off){ ls[t] += ls[t + off]; lq[t] += lq[t + off]; }
        __syncthreads();
    }
    float mu = ls[0] * (1.0f / 1048576.0f);
    float var = lq[0] * (1.0f / 1048576.0f) - mu * mu;
    float rs = rsqrtf(var + 1e-5f);
    __syncthreads();
    if (t < 64){
        int o = t & 31;
        const float* w = (t < 32) ? tgw : tbw;
        const float* bi = (t < 32) ? tgb : tbb;
        float a = bi[o];
        #pragma unroll
        for (int c = 0; c < 32; ++c) a += w[o * 32 + c] * tin[c];
        if (t < 32) GA[o] = a; else BE[o] = a;
    }
    __syncthreads();
    int n = blockIdx.x * 256 + t;
    float hv[32];
    #pragma unroll
    for (int c = 0; c < 32; ++c){
        float v = GA[c] * ((h2[c * NSP + n] - mu) * rs) + BE[c];
        hv[c] = v;
        h3[c * NSP + n] = v;
    }
    #pragma unroll
    for (int o = 0; o < 32; ++o){
        float aq = QB[o], ak = 0.f, av = 0.f;
        #pragma unroll
        for (int c = 0; c < 32; ++c){
            float v = hv[c];
            aq += QW[o * 32 + c] * v;
            ak += KW[o * 32 + c] * v;
            av += VW[o * 32 + c] * v;
        }
        Q[o * NSP + n] = aq;
        KH[o * NSP + n] = ak;
        VH[o * NSP + n] = av;
    }
}

__global__ void k_attn(const float* __restrict__ Q, const float* __restrict__ KH,
                       const float* __restrict__ VH,
                       const float* __restrict__ kb, const float* __restrict__ vb,
                       const float* __restrict__ mk, const float* __restrict__ mv,
                       float* __restrict__ out0){
    __shared__ float KL[3][1024], VL[3][1024];
    int bid = blockIdx.x;
    int swz = (bid & 7) * 128 + (bid >> 3);
    int c = swz >> 5, h_ = swz & 31;
    int t = threadIdx.x;
    #pragma unroll
    for (int p = 0; p < 3; ++p){
        int hh = h_ - 1 + p;
        if ((unsigned)hh < 32u){
            const float* sk = KH + (c * 32 + hh) * 1024;
            const float* sv = VH + (c * 32 + hh) * 1024;
            for (int j = t; j < 1024; j += 256){ KL[p][j] = sk[j]; VL[p][j] = sv[j]; }
        }
    }
    float kbc = kb[c], vbc = vb[c];
    float mkv[5], mvv[5];
    #pragma unroll
    for (int j = 0; j < 5; ++j){ mkv[j] = mk[c * 5 + j]; mvv[j] = mv[c * 5 + j]; }
    float qv[4];
    #pragma unroll
    for (int i = 0; i < 4; ++i) qv[i] = Q[c * NSP + h_ * 1024 + i * 256 + t];
    __syncthreads();
    const float scale = 0.17677669529663688f;
    #pragma unroll
    for (int i = 0; i < 4; ++i){
        int nl = i * 256 + t;
        int d_ = nl >> 5, w_ = nl & 31;
        float q = qv[i];
        float s = 0.f, acc = 0.f;
        #pragma unroll
        for (int j = 0; j < 5; ++j){
            float e = __expf(q * mkv[j] * scale);
            s += e; acc += e * mvv[j];
        }
        int oob = 0;
        #pragma unroll
        for (int p = 0; p < 3; ++p){
            int hh = h_ - 1 + p;
            if ((unsigned)hh >= 32u){ oob += 9; continue; }
            #pragma unroll
            for (int dj = -1; dj <= 1; ++dj){
                int dd = d_ + dj;
                if ((unsigned)dd >= 32u){ oob += 3; continue; }
                int rb = dd * 32;
                #pragma unroll
                for (int dl = -1; dl <= 1; ++dl){
                    int ww = w_ + dl;
                    if ((unsigned)ww < 32u){
                        float k = kbc + KL[p][rb + ww];
                        float v = vbc + VL[p][rb + ww];
                        float e = __expf(q * k * scale);
                        s += e; acc += e * v;
                    } else oob++;
                }
            }
        }
        float eb = __expf(q * kbc * scale);
        s += (float)oob * eb; acc += (float)oob * eb * vbc;
        out0[c * NSP + h_ * 1024 + nl] = acc / s;
    }
}

__global__ void k_gate(const float* __restrict__ h3, const float* __restrict__ out0,
                       const float* __restrict__ x,
                       const float* __restrict__ gw, const float* __restrict__ gb,
                       float* __restrict__ outp, float* __restrict__ mpart){
    __shared__ float GW[2048];
    __shared__ float FT[32 * 264];
    __shared__ float PS[256];
    int t = threadIdx.x;
    for (int j = t; j < 2048; j += 256) GW[j] = gw[j];
    int n = blockIdx.x * 256 + t;
    float hv[32], ov[32];
    #pragma unroll
    for (int c = 0; c < 32; ++c){ hv[c] = h3[c * NSP + n]; ov[c] = out0[c * NSP + n]; }
    __syncthreads();
    #pragma unroll
    for (int c = 0; c < 32; ++c){
        float g = gb[c];
        #pragma unroll
        for (int cc = 0; cc < 32; ++cc){
            g += GW[c * 64 + cc] * hv[cc] + GW[c * 64 + 32 + cc] * ov[cc];
        }
        g = sigmoidf_(g);
        float fin = g * ov[c] + (1.0f - g) * hv[c];
        FT[c * 264 + t] = fin;
        outp[c * NSP + n] = fin + geluf(x[c * NSP + n]);
    }
    __syncthreads();
    {
        int c8 = t >> 3, seg = t & 7;
        float s = 0.f;
        #pragma unroll
        for (int j = 0; j < 32; ++j) s += FT[c8 * 264 + seg * 32 + j];
        PS[t] = s;
    }
    __syncthreads();
    if (t < 32){
        float s = 0.f;
        #pragma unroll
        for (int j = 0; j < 8; ++j) s += PS[t * 8 + j];
        mpart[t * 128 + blockIdx.x] = s;
    }
}

__global__ void k_gru(const float* __restrict__ mpart, const float* __restrict__ pm,
                      const float* __restrict__ wih, const float* __restrict__ whh,
                      const float* __restrict__ bih, const float* __restrict__ bhh,
                      float* __restrict__ outp){
    __shared__ float PS[256];
    __shared__ float m_in[32], gi[96], gh[96];
    int t = threadIdx.x;
    {
        int c = t >> 3, seg = t & 7;
        float s = 0.f;
        #pragma unroll
        for (int j = 0; j < 16; ++j) s += mpart[c * 128 + seg * 16 + j];
        PS[t] = s;
    }
    __syncthreads();
    if (t < 32){
        float a = 0.f;
        #pragma unroll
        for (int j = 0; j < 8; ++j) a += PS[t * 8 + j];
        m_in[t] = a * (1.0f / 32768.0f);
    }
    __syncthreads();
    if (t < 96){
        float a = bih[t], b2 = bhh[t];
        #pragma unroll
        for (int cc = 0; cc < 32; ++cc){
            a += wih[t * 32 + cc] * m_in[cc];
            b2 += whh[t * 32 + cc] * pm[cc];
        }
        gi[t] = a; gh[t] = b2;
    }
    __syncthreads();
    if (t < 32){
        float r = sigmoidf_(gi[t] + gh[t]);
        float z = sigmoidf_(gi[32 + t] + gh[32 + t]);
        float nn = tanhf(gi[64 + t] + r * gh[64 + t]);
        float nm = (1.0f - z) * nn + z * pm[t];
        outp[1048576 + t] = nm;
    }
}

extern "C" void kernel_launch(void* const* d_in, const int* in_sizes, int n_in,
                              void* d_out, int out_size, void* d_ws, size_t ws_size,
                              hipStream_t stream){
    const float* x   = (const float*)d_in[0];
    const float* tin = (const float*)d_in[1];
    const float* pm  = (const float*)d_in[2];
    const float* wsr = (const float*)d_in[3];
    const float* wsi = (const float*)d_in[4];
    const float* n1g = (const float*)d_in[5];
    const float* n1b = (const float*)d_in[6];
    const float* mw1 = (const float*)d_in[7];
    const float* mb1 = (const float*)d_in[8];
    const float* mw2 = (const float*)d_in[9];
    const float* mb2 = (const float*)d_in[10];
    const float* tgw = (const float*)d_in[11];
    const float* tgb = (const float*)d_in[12];
    const float* tbw = (const float*)d_in[13];
    const float* tbb = (const float*)d_in[14];
    const float* qw  = (const float*)d_in[15];
    const float* qb  = (const float*)d_in[16];
    const float* kw  = (const float*)d_in[17];
    const float* kb  = (const float*)d_in[18];
    const float* vw  = (const float*)d_in[19];
    const float* vb  = (const float*)d_in[20];
    const float* mk  = (const float*)d_in[21];
    const float* mv  = (const float*)d_in[22];
    const float* gw  = (const float*)d_in[23];
    const float* gb  = (const float*)d_in[24];
    const float* wih = (const float*)d_in[25];
    const float* whh = (const float*)d_in[26];
    const float* bih = (const float*)d_in[27];
    const float* bhh = (const float*)d_in[28];

    float* ws = (float*)d_ws;
    float* Ar    = ws + 0;        // 524288
    float* Ai    = ws + 557056;
    float* Br    = ws + 1114112;
    float* Bi    = ws + 1671168;
    float* spec  = ws + 2228224;  // 1048576
    float* h1    = ws + 3276800;  // 1048576 (VH)
    float* h2    = ws + 4325376;  // 1048576
    float* h3    = ws + 5373952;  // 1048576
    float* psum  = ws + 6422784;  // 1024
    float* psq   = ws + 6423808;  // 1024
    float* psum2 = ws + 6424832;  // 1024
    float* psq2  = ws + 6425856;  // 1024
    // aliases (free by the time they're used)
    float* Cr    = h3;            // 524288 (modemul partial half 1) — h3 written later in k_qkv
    float* Ci    = h3 + 524288;
    float* Qb    = Br;    // free after k_inv
    float* KHb   = spec;  // free after k_mlp
    float* VHb   = h1;
    float* out0  = Ar;    // free after k_inv
    float* mpart = h2;    // 32*128, free after k_qkv

    float* outp = (float*)d_out;

    k_fwd    <<<1024, 256, 0, stream>>>(x, Br, Bi);            // T1 in Br/Bi
    k_fft_h  <<<1024, 256, 0, stream>>>(Br, Bi, Ar, Ai);
    k_modemul<<<1024, 256, 0, stream>>>(Ar, Ai, wsr, wsi, Br, Bi, Cr, Ci);
    k_ifft_h <<<1024, 256, 0, stream>>>(Br, Bi, Cr, Ci, Ar, Ai);
    k_inv    <<<1024, 256, 0, stream>>>(Ar, Ai, spec, psum, psq);
    k_mlp    <<<128, 256, 0, stream>>>(spec, x, n1g, n1b, psum, psq, mw1, mb1, mw2, mb2, h2, psum2, psq2);
    k_qkv    <<<128, 256, 0, stream>>>(h2, psum2, psq2, tin, tgw, tgb, tbw, tbb, qw, qb, kw, vw, h3, Qb, KHb, VHb);
    k_attn   <<<1024, 256, 0, stream>>>(Qb, KHb, VHb, kb, vb, mk, mv, out0);
    k_gate   <<<128, 256, 0, stream>>>(h3, out0, x, gw, gb, outp, mpart);
    k_gru    <<<1, 256, 0, stream>>>(mpart, pm, wih, whh, bih, bhh, outp);
}